// Round 13
// baseline (254.684 us; speedup 1.0000x reference)
//
#include <hip/hip_runtime.h>
#include <hip/hip_bf16.h>

#define NE 8
#define HD 1024
#define ID 2816
#define TT 4096
#define BM 128
#define BK 32
#define BN1 64
#define BN2 64
#define MAXMT (TT / BM + NE) /* 40 worst-case M-tiles */
#define NKS1 (HD / BK)  /* 32 */
#define NKS2 (ID / BK)  /* 88 */
#define ATILE 8192      /* BM*BK*2B fragment-order A tile */

typedef __attribute__((ext_vector_type(4))) float f32x4;
typedef __attribute__((ext_vector_type(8))) short s16x8;
typedef __attribute__((ext_vector_type(4))) int i32x4;

// fp32x2 -> packed bf16x2 (RNE, v_cvt_pk_bf16_f32)
__device__ __forceinline__ unsigned int f2bfpk(float lo, float hi) {
  float2 t; t.x = lo; t.y = hi;
  union { __hip_bfloat162 h2; unsigned int u; } cv;
  cv.h2 = __float22bfloat162_rn(t);
  return cv.u;
}

// async global->LDS, 16B per lane
__device__ __forceinline__ void glds16(const void* g, void* l) {
  __builtin_amdgcn_global_load_lds(
      (const __attribute__((address_space(1))) void*)g,
      (__attribute__((address_space(3))) void*)l, 16, 0, 0);
}

__device__ __forceinline__ bool map_tile(const void* bsp, int mt, int& e,
                                         int& mstart, int& rowend) {
  const int* w = (const int*)bsp;
  bool is64 = (w[1] == 0) && (w[3] == 0) && (w[5] == 0) && (w[7] == 0) &&
              ((w[0] | w[2] | w[4] | w[6]) != 0);
  long long start = 0;
  int rem = mt;
  for (int i = 0; i < NE; ++i) {
    long long b = is64 ? ((const long long*)bsp)[i] : (long long)w[i];
    if (b < 0) b = 0;
    int tiles = (int)((b + BM - 1) / BM);
    if (rem < tiles) {
      long long m0 = start + (long long)rem * BM;
      long long me = start + b;
      if (m0 >= TT) return false;
      if (me > TT) me = TT;
      e = i; mstart = (int)m0; rowend = (int)me;
      return true;
    }
    rem -= tiles;
    start += b;
  }
  return false;
}

// ---- Kernel 0: x fp32 -> bf16, pre-tiled in MFMA fragment order ----
__global__ __launch_bounds__(256) void cvt_xt(const float* __restrict__ x,
                                              const void* __restrict__ bsp,
                                              unsigned short* __restrict__ xt) {
  int mt = blockIdx.x >> 5;
  int ks = blockIdx.x & 31;
  int e, mstart, rowend;
  if (!map_tile(bsp, mt, e, mstart, rowend)) return;
  int t = threadIdx.x;
  int lane = t & 63;
  int r = lane & 15, q = lane >> 4;
  unsigned short* ob = xt + ((size_t)mt * NKS1 + ks) * (ATILE / 2);
#pragma unroll
  for (int h = 0; h < 2; ++h) {
    int f = h * 4 + (t >> 6);
    int row = mstart + f * 16 + r;
    s16x8 o = (s16x8)0;
    if (row < rowend) {
      const float* src = x + (size_t)row * HD + ks * 32 + q * 8;
      f32x4 v0 = *(const f32x4*)src;
      f32x4 v1 = *(const f32x4*)(src + 4);
      unsigned int d0 = f2bfpk(v0[0], v0[1]), d1 = f2bfpk(v0[2], v0[3]);
      unsigned int d2 = f2bfpk(v1[0], v1[1]), d3 = f2bfpk(v1[2], v1[3]);
      o[0] = (short)d0; o[1] = (short)(d0 >> 16);
      o[2] = (short)d1; o[3] = (short)(d1 >> 16);
      o[4] = (short)d2; o[5] = (short)(d2 >> 16);
      o[6] = (short)d3; o[7] = (short)(d3 >> 16);
    }
    *(s16x8*)(ob + h * 2048 + t * 8) = o;
  }
}

// ---------------- Kernel 1: up = silu(x@w1[e]) * (x@w3[e]) ----------------
// NT-INNER block order (this round's single change): consecutive logical
// blocks cover all 44 n-tiles of one mt, so co-resident blocks collectively
// stream FULL contiguous weight rows (dense HBM bursts instead of 256B/11KB
// strided chunks). mt-level weight re-reads now hit L3 (184MB < 256MB);
// same-mt blocks share the xt A-tile in L2.
__global__ __launch_bounds__(256, 3) void moe_gemm1(
    const unsigned short* __restrict__ xt, const float* __restrict__ w1,
    const float* __restrict__ w3, const void* __restrict__ bsp,
    __hip_bfloat16* __restrict__ up) {
  __shared__ __align__(16) char As[2][ATILE];   // 16384
  __shared__ __align__(16) char B1s[2][4096];   // 8192
  __shared__ __align__(16) char B3s[2][4096];   // 8192  -> 32KB

  const int NWG = (ID / BN1) * MAXMT;  // 1760, %8==0
  int bid = blockIdx.x;
  int logical = (bid & 7) * (NWG >> 3) + (bid >> 3);
  int nt = logical % (ID / BN1);   // nt-inner (was mt-inner)
  int mt = logical / (ID / BN1);
  int e, mstart, rowend;
  if (!map_tile(bsp, mt, e, mstart, rowend)) return;
  const int n0 = nt * BN1;
  const int tid = threadIdx.x;
  const int lane = tid & 63;
  const int wv = tid >> 6;
  const int wr = wv >> 1, wc = wv & 1;
  const int q = lane >> 4, r16 = lane & 15;

  const int b_n = tid & 63, b_kq = tid >> 6;
  const int boff = (b_n >> 4) * 1024 + b_kq * 256 + (b_n & 15) * 16;
  const char* agp = (const char*)xt + (size_t)mt * NKS1 * ATILE + tid * 16;
  const float* w1c = w1 + (size_t)e * HD * ID + (size_t)(8 * b_kq) * ID + n0 + b_n;
  const float* w3c = w3 + (size_t)e * HD * ID + (size_t)(8 * b_kq) * ID + n0 + b_n;

  f32x4 acc1[4][2], acc3[4][2];
#pragma unroll
  for (int i = 0; i < 4; ++i)
#pragma unroll
    for (int j = 0; j < 2; ++j) { acc1[i][j] = (f32x4)0.f; acc3[i][j] = (f32x4)0.f; }

  float Wa1[8], Wa3[8], Wb1[8], Wb3[8];  // 2-deep W ring

  auto gldsA = [&](int k, int buf) {
    const char* s = agp + (size_t)k * ATILE;
    char* d = &As[buf][0] + tid * 16;
    glds16(s, d);
    glds16(s + 4096, d + 4096);
  };
  auto loadB = [&](float* W1_, float* W3_) {
#pragma unroll
    for (int i = 0; i < 8; ++i) {
      W1_[i] = w1c[(size_t)i * ID];
      W3_[i] = w3c[(size_t)i * ID];
    }
    w1c += (size_t)BK * ID; w3c += (size_t)BK * ID;
  };
  auto storeB = [&](int buf, const float* W1_, const float* W3_) {
    i32x4 p1, p3;
    p1[0] = (int)f2bfpk(W1_[0], W1_[1]); p1[1] = (int)f2bfpk(W1_[2], W1_[3]);
    p1[2] = (int)f2bfpk(W1_[4], W1_[5]); p1[3] = (int)f2bfpk(W1_[6], W1_[7]);
    *(i32x4*)(B1s[buf] + boff) = p1;
    p3[0] = (int)f2bfpk(W3_[0], W3_[1]); p3[1] = (int)f2bfpk(W3_[2], W3_[3]);
    p3[2] = (int)f2bfpk(W3_[4], W3_[5]); p3[3] = (int)f2bfpk(W3_[6], W3_[7]);
    *(i32x4*)(B3s[buf] + boff) = p3;
  };
  auto compute = [&](int ab, int bb) {
    s16x8 a[4], b1[2], b3[2];
#pragma unroll
    for (int i = 0; i < 4; ++i)
      a[i] = *(const s16x8*)(As[ab] + (wr * 4 + i) * 1024 + lane * 16);
#pragma unroll
    for (int j = 0; j < 2; ++j) {
      b1[j] = *(const s16x8*)(B1s[bb] + (wc * 2 + j) * 1024 + lane * 16);
      b3[j] = *(const s16x8*)(B3s[bb] + (wc * 2 + j) * 1024 + lane * 16);
    }
#pragma unroll
    for (int i = 0; i < 4; ++i)
#pragma unroll
      for (int j = 0; j < 2; ++j) {
        acc1[i][j] = __builtin_amdgcn_mfma_f32_16x16x32_bf16(a[i], b1[j], acc1[i][j], 0, 0, 0);
        acc3[i][j] = __builtin_amdgcn_mfma_f32_16x16x32_bf16(a[i], b3[j], acc3[i][j], 0, 0, 0);
      }
  };

// phase p (P=p&1): glds A(p+1), loadB W(p+2)->W[P], compute(p),
// storeB W(p+1) from W[P^1], vmcnt(16|0)+barrier.
#define G1PHASE(P, KC)                                                    \
  {                                                                       \
    const bool doG = (kt + (KC) + 1 < NKS1);                              \
    const bool doL = (kt + (KC) + 2 < NKS1);                              \
    if (doG) {                                                            \
      gldsA(kt + (KC) + 1, (P) ^ 1);                                      \
      __builtin_amdgcn_sched_barrier(0);                                  \
    }                                                                     \
    if (doL) {                                                            \
      loadB((P) ? Wb1 : Wa1, (P) ? Wb3 : Wa3);                            \
      __builtin_amdgcn_sched_barrier(0);                                  \
    }                                                                     \
    compute((P), (P));                                                    \
    if (doG) {                                                            \
      storeB((P) ^ 1, (P) ? Wa1 : Wb1, (P) ? Wa3 : Wb3);                  \
      if (doL)                                                            \
        asm volatile("s_waitcnt vmcnt(16) lgkmcnt(0)" ::: "memory");      \
      else                                                                \
        asm volatile("s_waitcnt vmcnt(0) lgkmcnt(0)" ::: "memory");       \
      __builtin_amdgcn_s_barrier();                                       \
    }                                                                     \
  }

  // prologue: glds(0); W(0)->Wa; W(1)->Wb; storeB(0 from Wa); drain; barrier
  gldsA(0, 0);
  __builtin_amdgcn_sched_barrier(0);
  loadB(Wa1, Wa3);
  __builtin_amdgcn_sched_barrier(0);
  loadB(Wb1, Wb3);
  storeB(0, Wa1, Wa3);
  asm volatile("s_waitcnt vmcnt(16) lgkmcnt(0)" ::: "memory");
  __builtin_amdgcn_s_barrier();

  for (int kt = 0; kt < NKS1; kt += 2) {
    G1PHASE(0, 0)
    G1PHASE(1, 1)
  }
#undef G1PHASE

  // epilogue: silu(acc1)*acc3 -> bf16
#pragma unroll
  for (int i = 0; i < 4; ++i)
#pragma unroll
    for (int r = 0; r < 4; ++r) {
      int gm = mstart + wr * 64 + i * 16 + q * 4 + r;
      if (gm < rowend) {
#pragma unroll
        for (int j = 0; j < 2; ++j) {
          float v1 = acc1[i][j][r], v3 = acc3[i][j][r];
          float s = v1 / (1.f + __expf(-v1));
          up[(size_t)gm * ID + n0 + wc * 32 + j * 16 + r16] = __float2bfloat16(s * v3);
        }
      }
    }
}

// ---------------- Kernel 2: out = up @ w2[e] ----------------
// Same nt-inner change; rest identical to round 12.
__global__ __launch_bounds__(256, 4) void moe_gemm2(
    const __hip_bfloat16* __restrict__ up, const float* __restrict__ w2,
    const void* __restrict__ bsp, float* __restrict__ out) {
  __shared__ __align__(16) char As[2][ATILE];  // 16384
  __shared__ __align__(16) char Bs[2][4096];   // 8192 -> 24KB

  const int NWG = (HD / BN2) * MAXMT;  // 640, %8==0
  int bid = blockIdx.x;
  int logical = (bid & 7) * (NWG >> 3) + (bid >> 3);
  int nt = logical % (HD / BN2);   // nt-inner
  int mt = logical / (HD / BN2);
  int e, mstart, rowend;
  if (!map_tile(bsp, mt, e, mstart, rowend)) return;
  const int n0 = nt * BN2;
  const int tid = threadIdx.x;
  const int lane = tid & 63;
  const int wv = tid >> 6;
  const int wr = wv >> 1, wc = wv & 1;
  const int q = lane >> 4, r16 = lane & 15;

  const int b_n = tid & 63, b_kq = tid >> 6;
  const int boff = (b_n >> 4) * 1024 + b_kq * 256 + (b_n & 15) * 16;
  const float* w2c = w2 + (size_t)e * ID * HD + (size_t)(8 * b_kq) * HD + n0 + b_n;

  int row0 = mstart + (tid >> 6) * 16 + (tid & 15);
  int row1 = row0 + 64;
  row0 = row0 < TT ? row0 : TT - 1;
  row1 = row1 < TT ? row1 : TT - 1;
  const char* uc0 = (const char*)up + ((size_t)row0 * ID + q * 8) * 2;
  const char* uc1 = (const char*)up + ((size_t)row1 * ID + q * 8) * 2;

  f32x4 acc[4][2];
#pragma unroll
  for (int i = 0; i < 4; ++i)
#pragma unroll
    for (int j = 0; j < 2; ++j) acc[i][j] = (f32x4)0.f;

  float Wa[8], Wb[8];

  auto gldsA = [&](int buf) {  // sequential k; cursors advance 64B/call
    char* d = &As[buf][0] + tid * 16;
    glds16(uc0, d);
    glds16(uc1, d + 4096);
    uc0 += BK * 2; uc1 += BK * 2;
  };
  auto loadB = [&](float* W_) {
#pragma unroll
    for (int i = 0; i < 8; ++i) W_[i] = w2c[(size_t)i * HD];
    w2c += (size_t)BK * HD;
  };
  auto storeB = [&](int buf, const float* W_) {
    i32x4 p;
    p[0] = (int)f2bfpk(W_[0], W_[1]); p[1] = (int)f2bfpk(W_[2], W_[3]);
    p[2] = (int)f2bfpk(W_[4], W_[5]); p[3] = (int)f2bfpk(W_[6], W_[7]);
    *(i32x4*)(Bs[buf] + boff) = p;
  };
  auto compute = [&](int ab, int bb) {
    s16x8 a[4], b[2];
#pragma unroll
    for (int i = 0; i < 4; ++i)
      a[i] = *(const s16x8*)(As[ab] + (wr * 4 + i) * 1024 + lane * 16);
#pragma unroll
    for (int j = 0; j < 2; ++j)
      b[j] = *(const s16x8*)(Bs[bb] + (wc * 2 + j) * 1024 + lane * 16);
#pragma unroll
    for (int i = 0; i < 4; ++i)
#pragma unroll
      for (int j = 0; j < 2; ++j)
        acc[i][j] = __builtin_amdgcn_mfma_f32_16x16x32_bf16(a[i], b[j], acc[i][j], 0, 0, 0);
  };

#define G2PHASE(P, KC)                                                    \
  {                                                                       \
    const bool doG = (kt + (KC) + 1 < NKS2);                              \
    const bool doL = (kt + (KC) + 2 < NKS2);                              \
    if (doG) {                                                            \
      gldsA((P) ^ 1);                                                     \
      __builtin_amdgcn_sched_barrier(0);                                  \
    }                                                                     \
    if (doL) {                                                            \
      loadB((P) ? Wb : Wa);                                               \
      __builtin_amdgcn_sched_barrier(0);                                  \
    }                                                                     \
    compute((P), (P));                                                    \
    if (doG) {                                                            \
      storeB((P) ^ 1, (P) ? Wa : Wb);                                     \
      if (doL)                                                            \
        asm volatile("s_waitcnt vmcnt(8) lgkmcnt(0)" ::: "memory");       \
      else                                                                \
        asm volatile("s_waitcnt vmcnt(0) lgkmcnt(0)" ::: "memory");       \
      __builtin_amdgcn_s_barrier();                                       \
    }                                                                     \
  }

  gldsA(0);
  __builtin_amdgcn_sched_barrier(0);
  loadB(Wa);
  __builtin_amdgcn_sched_barrier(0);
  loadB(Wb);
  storeB(0, Wa);
  asm volatile("s_waitcnt vmcnt(8) lgkmcnt(0)" ::: "memory");
  __builtin_amdgcn_s_barrier();

  for (int kt = 0; kt < NKS2; kt += 2) {
    G2PHASE(0, 0)
    G2PHASE(1, 1)
  }
#undef G2PHASE

#pragma unroll
  for (int i = 0; i < 4; ++i)
#pragma unroll
    for (int r = 0; r < 4; ++r) {
      int gm = mstart + wr * 64 + i * 16 + q * 4 + r;
      if (gm < rowend) {
#pragma unroll
        for (int j = 0; j < 2; ++j)
          out[(size_t)gm * HD + n0 + wc * 32 + j * 16 + r16] = acc[i][j][r];
      }
    }
}

extern "C" void kernel_launch(void* const* d_in, const int* in_sizes, int n_in,
                              void* d_out, int out_size, void* d_ws, size_t ws_size,
                              hipStream_t stream) {
  const float* x = (const float*)d_in[0];
  const float* w1 = (const float*)d_in[1];
  const float* w2 = (const float*)d_in[2];
  const float* w3 = (const float*)d_in[3];
  const void* bs = d_in[4];
  float* out = (float*)d_out;
  // ws: xt tiled [10.49 MB] | up [23.07 MB]
  unsigned short* xt = (unsigned short*)d_ws;
  __hip_bfloat16* up =
      (__hip_bfloat16*)((char*)d_ws + (size_t)MAXMT * NKS1 * ATILE);

  hipMemsetAsync(d_out, 0, (size_t)out_size * sizeof(float), stream);

  cvt_xt<<<dim3(MAXMT * NKS1), dim3(256), 0, stream>>>(x, bs, xt);
  moe_gemm1<<<dim3((ID / BN1) * MAXMT), dim3(256), 0, stream>>>(xt, w1, w3, bs, up);
  moe_gemm2<<<dim3((HD / BN2) * MAXMT), dim3(256), 0, stream>>>(up, w2, bs, out);
}

// Round 14
// 199.708 us; speedup vs baseline: 1.2753x; 1.2753x over previous
//
#include <hip/hip_runtime.h>
#include <hip/hip_bf16.h>

#define NE 8
#define HD 1024
#define ID 2816
#define TT 4096
#define BM 128
#define BK 32
#define BN1 64
#define BN2 64
#define MAXMT (TT / BM + NE) /* 40 worst-case M-tiles */
#define NKS1 (HD / BK)  /* 32 */
#define NKS2 (ID / BK)  /* 88 */
#define ATILE 8192      /* BM*BK*2B fragment-order A tile */
#define GS 1040         /* B group stride: 1024 + 16 pad (write-conflict-free) */
#define BT (4 * GS)     /* 4160 B per B tile */

typedef __attribute__((ext_vector_type(4))) float f32x4;
typedef __attribute__((ext_vector_type(8))) short s16x8;

// fp32x2 -> packed bf16x2 (RNE, v_cvt_pk_bf16_f32)
__device__ __forceinline__ unsigned int f2bfpk(float lo, float hi) {
  float2 t; t.x = lo; t.y = hi;
  union { __hip_bfloat162 h2; unsigned int u; } cv;
  cv.h2 = __float22bfloat162_rn(t);
  return cv.u;
}

// async global->LDS, 16B per lane
__device__ __forceinline__ void glds16(const void* g, void* l) {
  __builtin_amdgcn_global_load_lds(
      (const __attribute__((address_space(1))) void*)g,
      (__attribute__((address_space(3))) void*)l, 16, 0, 0);
}

__device__ __forceinline__ bool map_tile(const void* bsp, int mt, int& e,
                                         int& mstart, int& rowend) {
  const int* w = (const int*)bsp;
  bool is64 = (w[1] == 0) && (w[3] == 0) && (w[5] == 0) && (w[7] == 0) &&
              ((w[0] | w[2] | w[4] | w[6]) != 0);
  long long start = 0;
  int rem = mt;
  for (int i = 0; i < NE; ++i) {
    long long b = is64 ? ((const long long*)bsp)[i] : (long long)w[i];
    if (b < 0) b = 0;
    int tiles = (int)((b + BM - 1) / BM);
    if (rem < tiles) {
      long long m0 = start + (long long)rem * BM;
      long long me = start + b;
      if (m0 >= TT) return false;
      if (me > TT) me = TT;
      e = i; mstart = (int)m0; rowend = (int)me;
      return true;
    }
    rem -= tiles;
    start += b;
  }
  return false;
}

// ---- Kernel 0: x fp32 -> bf16, pre-tiled in MFMA fragment order ----
__global__ __launch_bounds__(256) void cvt_xt(const float* __restrict__ x,
                                              const void* __restrict__ bsp,
                                              unsigned short* __restrict__ xt) {
  int mt = blockIdx.x >> 5;
  int ks = blockIdx.x & 31;
  int e, mstart, rowend;
  if (!map_tile(bsp, mt, e, mstart, rowend)) return;
  int t = threadIdx.x;
  int lane = t & 63;
  int r = lane & 15, q = lane >> 4;
  unsigned short* ob = xt + ((size_t)mt * NKS1 + ks) * (ATILE / 2);
#pragma unroll
  for (int h = 0; h < 2; ++h) {
    int f = h * 4 + (t >> 6);
    int row = mstart + f * 16 + r;
    s16x8 o = (s16x8)0;
    if (row < rowend) {
      const float* src = x + (size_t)row * HD + ks * 32 + q * 8;
      f32x4 v0 = *(const f32x4*)src;
      f32x4 v1 = *(const f32x4*)(src + 4);
      unsigned int d0 = f2bfpk(v0[0], v0[1]), d1 = f2bfpk(v0[2], v0[3]);
      unsigned int d2 = f2bfpk(v1[0], v1[1]), d3 = f2bfpk(v1[2], v1[3]);
      o[0] = (short)d0; o[1] = (short)(d0 >> 16);
      o[2] = (short)d1; o[3] = (short)(d1 >> 16);
      o[4] = (short)d2; o[5] = (short)(d2 >> 16);
      o[6] = (short)d3; o[7] = (short)(d3 >> 16);
    }
    *(s16x8*)(ob + h * 2048 + t * 8) = o;
  }
}

// ---------------- Kernel 1: up = silu(x@w1[e]) * (x@w3[e]) ----------------
// THIS ROUND: weight loads are n-contiguous float4 (4 cols x 2 k per thread,
// 2 dwordx4 per matrix per phase = 4x fewer VMEM instrs at 4x bytes/instr;
// the ~1.6 TB/s cap matched 4B/lane instruction-rate). fp32->bf16 k-pair
// transpose happens in the LDS write: per col cvt_pk(k,k+1) -> b32 at
// g*GS + (k>>3)*256 + (n&15)*16 + (k&7)*2. GS=1040 -> writes 2 lanes/bank
// (free), b128 frag reads unchanged. Rest = round 12 (mt-inner, As[2]
// glds-1-ahead, counted vmcnt: 4 = this phase's W loads).
__global__ __launch_bounds__(256, 3) void moe_gemm1(
    const unsigned short* __restrict__ xt, const float* __restrict__ w1,
    const float* __restrict__ w3, const void* __restrict__ bsp,
    __hip_bfloat16* __restrict__ up) {
  __shared__ __align__(16) char As[2][ATILE];  // 16384
  __shared__ __align__(16) char B1s[2][BT];    // 8320
  __shared__ __align__(16) char B3s[2][BT];    // 8320  -> 33KB

  const int NWG = (ID / BN1) * MAXMT;  // 1760, %8==0
  int bid = blockIdx.x;
  int logical = (bid & 7) * (NWG >> 3) + (bid >> 3);
  int mt = logical % MAXMT;            // mt-inner (round 12; round 13 nt-inner was worse)
  int nt = logical / MAXMT;
  int e, mstart, rowend;
  if (!map_tile(bsp, mt, e, mstart, rowend)) return;
  const int n0 = nt * BN1;
  const int tid = threadIdx.x;
  const int lane = tid & 63;
  const int wv = tid >> 6;
  const int wr = wv >> 1, wc = wv & 1;
  const int q = lane >> 4, r16 = lane & 15;

  // B staging: thread owns cols c4*4..+3, k = 2*kb, 2*kb+1
  const int c4 = tid & 15, kb = tid >> 4;  // kb 0..15
  const int wbase = (c4 >> 2) * GS + (kb >> 2) * 256 + (c4 & 3) * 64 + (kb & 3) * 4;
  const char* agp = (const char*)xt + (size_t)mt * NKS1 * ATILE + tid * 16;
  const float* w1c = w1 + (size_t)e * HD * ID + (size_t)(2 * kb) * ID + n0 + c4 * 4;
  const float* w3c = w3 + (size_t)e * HD * ID + (size_t)(2 * kb) * ID + n0 + c4 * 4;

  f32x4 acc1[4][2], acc3[4][2];
#pragma unroll
  for (int i = 0; i < 4; ++i)
#pragma unroll
    for (int j = 0; j < 2; ++j) { acc1[i][j] = (f32x4)0.f; acc3[i][j] = (f32x4)0.f; }

  f32x4 Wa[4], Wb[4];  // [0,1]=w1 k,k+1 ; [2,3]=w3 k,k+1 (2-deep ring)

  auto gldsA = [&](int k, int buf) {
    const char* s = agp + (size_t)k * ATILE;
    char* d = &As[buf][0] + tid * 16;
    glds16(s, d);
    glds16(s + 4096, d + 4096);
  };
  auto loadB = [&](f32x4* W) {
    W[0] = *(const f32x4*)w1c;
    W[1] = *(const f32x4*)(w1c + ID);
    W[2] = *(const f32x4*)w3c;
    W[3] = *(const f32x4*)(w3c + ID);
    w1c += (size_t)BK * ID; w3c += (size_t)BK * ID;
  };
  auto storeB = [&](int buf, const f32x4* W) {
#pragma unroll
    for (int ci = 0; ci < 4; ++ci) {
      *(unsigned int*)(B1s[buf] + wbase + ci * 16) = f2bfpk(W[0][ci], W[1][ci]);
      *(unsigned int*)(B3s[buf] + wbase + ci * 16) = f2bfpk(W[2][ci], W[3][ci]);
    }
  };
  auto compute = [&](int ab, int bb) {
    s16x8 a[4], b1[2], b3[2];
#pragma unroll
    for (int i = 0; i < 4; ++i)
      a[i] = *(const s16x8*)(As[ab] + (wr * 4 + i) * 1024 + lane * 16);
#pragma unroll
    for (int j = 0; j < 2; ++j) {
      b1[j] = *(const s16x8*)(B1s[bb] + (wc * 2 + j) * GS + lane * 16);
      b3[j] = *(const s16x8*)(B3s[bb] + (wc * 2 + j) * GS + lane * 16);
    }
#pragma unroll
    for (int i = 0; i < 4; ++i)
#pragma unroll
      for (int j = 0; j < 2; ++j) {
        acc1[i][j] = __builtin_amdgcn_mfma_f32_16x16x32_bf16(a[i], b1[j], acc1[i][j], 0, 0, 0);
        acc3[i][j] = __builtin_amdgcn_mfma_f32_16x16x32_bf16(a[i], b3[j], acc3[i][j], 0, 0, 0);
      }
  };

// phase p (P=p&1): glds A(p+1), loadB W(p+2)->W[P], compute(p),
// storeB W(p+1) from W[P^1], vmcnt(4|0)+barrier (4 = this phase's W loads).
#define G1PHASE(P, KC)                                                    \
  {                                                                       \
    const bool doG = (kt + (KC) + 1 < NKS1);                              \
    const bool doL = (kt + (KC) + 2 < NKS1);                              \
    if (doG) {                                                            \
      gldsA(kt + (KC) + 1, (P) ^ 1);                                      \
      __builtin_amdgcn_sched_barrier(0);                                  \
    }                                                                     \
    if (doL) {                                                            \
      loadB((P) ? Wb : Wa);                                               \
      __builtin_amdgcn_sched_barrier(0);                                  \
    }                                                                     \
    compute((P), (P));                                                    \
    if (doG) {                                                            \
      storeB((P) ^ 1, (P) ? Wa : Wb);                                     \
      if (doL)                                                            \
        asm volatile("s_waitcnt vmcnt(4) lgkmcnt(0)" ::: "memory");       \
      else                                                                \
        asm volatile("s_waitcnt vmcnt(0) lgkmcnt(0)" ::: "memory");       \
      __builtin_amdgcn_s_barrier();                                       \
    }                                                                     \
  }

  // prologue: glds(0); W(0)->Wa; W(1)->Wb; storeB(0 from Wa); drain; barrier
  gldsA(0, 0);
  __builtin_amdgcn_sched_barrier(0);
  loadB(Wa);
  __builtin_amdgcn_sched_barrier(0);
  loadB(Wb);
  storeB(0, Wa);
  asm volatile("s_waitcnt vmcnt(4) lgkmcnt(0)" ::: "memory");
  __builtin_amdgcn_s_barrier();

  for (int kt = 0; kt < NKS1; kt += 2) {
    G1PHASE(0, 0)
    G1PHASE(1, 1)
  }
#undef G1PHASE

  // epilogue: silu(acc1)*acc3 -> bf16
#pragma unroll
  for (int i = 0; i < 4; ++i)
#pragma unroll
    for (int r = 0; r < 4; ++r) {
      int gm = mstart + wr * 64 + i * 16 + q * 4 + r;
      if (gm < rowend) {
#pragma unroll
        for (int j = 0; j < 2; ++j) {
          float v1 = acc1[i][j][r], v3 = acc3[i][j][r];
          float s = v1 / (1.f + __expf(-v1));
          up[(size_t)gm * ID + n0 + wc * 32 + j * 16 + r16] = __float2bfloat16(s * v3);
        }
      }
    }
}

// ---------------- Kernel 2: out = up @ w2[e] ----------------
// Same float4 weight staging (2 dwordx4/thread/phase); A glds'd from
// row-major `up` with per-lane frag-order sources. 24.6KB LDS.
__global__ __launch_bounds__(256, 4) void moe_gemm2(
    const __hip_bfloat16* __restrict__ up, const float* __restrict__ w2,
    const void* __restrict__ bsp, float* __restrict__ out) {
  __shared__ __align__(16) char As[2][ATILE];  // 16384
  __shared__ __align__(16) char Bs[2][BT];     // 8320 -> 24.7KB

  const int NWG = (HD / BN2) * MAXMT;  // 640, %8==0
  int bid = blockIdx.x;
  int logical = (bid & 7) * (NWG >> 3) + (bid >> 3);
  int mt = logical % MAXMT;            // mt-inner
  int nt = logical / MAXMT;
  int e, mstart, rowend;
  if (!map_tile(bsp, mt, e, mstart, rowend)) return;
  const int n0 = nt * BN2;
  const int tid = threadIdx.x;
  const int lane = tid & 63;
  const int wv = tid >> 6;
  const int wr = wv >> 1, wc = wv & 1;
  const int q = lane >> 4, r16 = lane & 15;

  const int c4 = tid & 15, kb = tid >> 4;
  const int wbase = (c4 >> 2) * GS + (kb >> 2) * 256 + (c4 & 3) * 64 + (kb & 3) * 4;
  const float* w2c = w2 + (size_t)e * ID * HD + (size_t)(2 * kb) * HD + n0 + c4 * 4;

  int row0 = mstart + (tid >> 6) * 16 + (tid & 15);
  int row1 = row0 + 64;
  row0 = row0 < TT ? row0 : TT - 1;
  row1 = row1 < TT ? row1 : TT - 1;
  const char* uc0 = (const char*)up + ((size_t)row0 * ID + q * 8) * 2;
  const char* uc1 = (const char*)up + ((size_t)row1 * ID + q * 8) * 2;

  f32x4 acc[4][2];
#pragma unroll
  for (int i = 0; i < 4; ++i)
#pragma unroll
    for (int j = 0; j < 2; ++j) acc[i][j] = (f32x4)0.f;

  f32x4 Wa[2], Wb[2];

  auto gldsA = [&](int buf) {  // sequential k; cursors advance 64B/call
    char* d = &As[buf][0] + tid * 16;
    glds16(uc0, d);
    glds16(uc1, d + 4096);
    uc0 += BK * 2; uc1 += BK * 2;
  };
  auto loadB = [&](f32x4* W) {
    W[0] = *(const f32x4*)w2c;
    W[1] = *(const f32x4*)(w2c + HD);
    w2c += (size_t)BK * HD;
  };
  auto storeB = [&](int buf, const f32x4* W) {
#pragma unroll
    for (int ci = 0; ci < 4; ++ci)
      *(unsigned int*)(Bs[buf] + wbase + ci * 16) = f2bfpk(W[0][ci], W[1][ci]);
  };
  auto compute = [&](int ab, int bb) {
    s16x8 a[4], b[2];
#pragma unroll
    for (int i = 0; i < 4; ++i)
      a[i] = *(const s16x8*)(As[ab] + (wr * 4 + i) * 1024 + lane * 16);
#pragma unroll
    for (int j = 0; j < 2; ++j)
      b[j] = *(const s16x8*)(Bs[bb] + (wc * 2 + j) * GS + lane * 16);
#pragma unroll
    for (int i = 0; i < 4; ++i)
#pragma unroll
      for (int j = 0; j < 2; ++j)
        acc[i][j] = __builtin_amdgcn_mfma_f32_16x16x32_bf16(a[i], b[j], acc[i][j], 0, 0, 0);
  };

#define G2PHASE(P, KC)                                                    \
  {                                                                       \
    const bool doG = (kt + (KC) + 1 < NKS2);                              \
    const bool doL = (kt + (KC) + 2 < NKS2);                              \
    if (doG) {                                                            \
      gldsA((P) ^ 1);                                                     \
      __builtin_amdgcn_sched_barrier(0);                                  \
    }                                                                     \
    if (doL) {                                                            \
      loadB((P) ? Wb : Wa);                                               \
      __builtin_amdgcn_sched_barrier(0);                                  \
    }                                                                     \
    compute((P), (P));                                                    \
    if (doG) {                                                            \
      storeB((P) ^ 1, (P) ? Wa : Wb);                                     \
      if (doL)                                                            \
        asm volatile("s_waitcnt vmcnt(2) lgkmcnt(0)" ::: "memory");       \
      else                                                                \
        asm volatile("s_waitcnt vmcnt(0) lgkmcnt(0)" ::: "memory");       \
      __builtin_amdgcn_s_barrier();                                       \
    }                                                                     \
  }

  gldsA(0);
  __builtin_amdgcn_sched_barrier(0);
  loadB(Wa);
  __builtin_amdgcn_sched_barrier(0);
  loadB(Wb);
  storeB(0, Wa);
  asm volatile("s_waitcnt vmcnt(2) lgkmcnt(0)" ::: "memory");
  __builtin_amdgcn_s_barrier();

  for (int kt = 0; kt < NKS2; kt += 2) {
    G2PHASE(0, 0)
    G2PHASE(1, 1)
  }
#undef G2PHASE

#pragma unroll
  for (int i = 0; i < 4; ++i)
#pragma unroll
    for (int r = 0; r < 4; ++r) {
      int gm = mstart + wr * 64 + i * 16 + q * 4 + r;
      if (gm < rowend) {
#pragma unroll
        for (int j = 0; j < 2; ++j)
          out[(size_t)gm * HD + n0 + wc * 32 + j * 16 + r16] = acc[i][j][r];
      }
    }
}

extern "C" void kernel_launch(void* const* d_in, const int* in_sizes, int n_in,
                              void* d_out, int out_size, void* d_ws, size_t ws_size,
                              hipStream_t stream) {
  const float* x = (const float*)d_in[0];
  const float* w1 = (const float*)d_in[1];
  const float* w2 = (const float*)d_in[2];
  const float* w3 = (const float*)d_in[3];
  const void* bs = d_in[4];
  float* out = (float*)d_out;
  // ws: xt tiled [10.49 MB] | up [23.07 MB]
  unsigned short* xt = (unsigned short*)d_ws;
  __hip_bfloat16* up =
      (__hip_bfloat16*)((char*)d_ws + (size_t)MAXMT * NKS1 * ATILE);

  hipMemsetAsync(d_out, 0, (size_t)out_size * sizeof(float), stream);

  cvt_xt<<<dim3(MAXMT * NKS1), dim3(256), 0, stream>>>(x, bs, xt);
  moe_gemm1<<<dim3((ID / BN1) * MAXMT), dim3(256), 0, stream>>>(xt, w1, w3, bs, up);
  moe_gemm2<<<dim3((HD / BN2) * MAXMT), dim3(256), 0, stream>>>(up, w2, bs, out);
}